// Round 1
// baseline (154.723 us; speedup 1.0000x reference)
//
#include <hip/hip_runtime.h>

// Problem constants
#define BB   256
#define TT   2048
#define FTR  128
#define FST  64
#define HH   3
#define NOUT 32
#define TBSZ (TT * BB)
#define PF   16   // k2 register prefetch depth (steps)

// ---------------------------------------------------------------------------
// k1: c[(t*B+b)] = float4(xW[b,t,0..2] + b_ih + b_hh, <unused>)
// 16 lanes per (b,t) row, 4 rows per wave. Coalesced float4 reads of tr_input,
// shfl_xor butterfly reduction over 16 lanes for the 3 dot products.
// ---------------------------------------------------------------------------
__global__ __launch_bounds__(256) void k1_proj(
    const float* __restrict__ tr,      // [B][T][128]
    const float* __restrict__ W_ih,    // [3][128]
    const float* __restrict__ b_ih,    // [3]
    const float* __restrict__ b_hh,    // [3]
    float* __restrict__ c)             // [T*B] float4 (stored as floats)
{
    const int lane = threadIdx.x & 63;
    const int sub  = lane & 15;        // element slice within row
    const int quad = lane >> 4;        // which of 4 rows in the group
    const int wave   = blockIdx.x * (blockDim.x >> 6) + (threadIdx.x >> 6);
    const int nwaves = gridDim.x * (blockDim.x >> 6);

    const float4* W4 = reinterpret_cast<const float4*>(W_ih);  // [3][32]
    const float4 wA0 = W4[       sub], wA1 = W4[16 + sub];
    const float4 wB0 = W4[32   + sub], wB1 = W4[48 + sub];
    const float4 wC0 = W4[64   + sub], wC1 = W4[80 + sub];
    const float bias = (sub < 3) ? (b_ih[sub] + b_hh[sub]) : 0.0f;

    const float4* in4 = reinterpret_cast<const float4*>(tr);
    const int ngroups = TBSZ / 4;      // group = 4 consecutive b at same t
    for (int g = wave; g < ngroups; g += nwaves) {
        const int t = g >> 6;                    // g / 64
        const int b = ((g & 63) << 2) + quad;    // 4 consecutive b per group
        const int rowb = (b * TT + t) * (FTR / 4);
        const float4 x0 = in4[rowb + sub];       // elems 4*sub .. 4*sub+3
        const float4 x1 = in4[rowb + 16 + sub];  // elems 64+4*sub ..
        float p0 = x0.x*wA0.x + x0.y*wA0.y + x0.z*wA0.z + x0.w*wA0.w
                 + x1.x*wA1.x + x1.y*wA1.y + x1.z*wA1.z + x1.w*wA1.w;
        float p1 = x0.x*wB0.x + x0.y*wB0.y + x0.z*wB0.z + x0.w*wB0.w
                 + x1.x*wB1.x + x1.y*wB1.y + x1.z*wB1.z + x1.w*wB1.w;
        float p2 = x0.x*wC0.x + x0.y*wC0.y + x0.z*wC0.z + x0.w*wC0.w
                 + x1.x*wC1.x + x1.y*wC1.y + x1.z*wC1.z + x1.w*wC1.w;
        #pragma unroll
        for (int m = 1; m <= 8; m <<= 1) {       // 16-lane butterfly (DPP-able)
            p0 += __shfl_xor(p0, m);
            p1 += __shfl_xor(p1, m);
            p2 += __shfl_xor(p2, m);
        }
        if (sub < 3) {
            const float v = (sub == 0) ? p0 : ((sub == 1) ? p1 : p2);
            c[((t * BB + b) << 2) + sub] = v + bias;
        }
    }
}

// ---------------------------------------------------------------------------
// k2: sequential relu-RNN scan, one lane per batch element, plus FC epilogue.
// Register prefetch ring of PF float4s, statically indexed (fully unrolled).
// ---------------------------------------------------------------------------
__global__ __launch_bounds__(64) void k2_scan(
    const float4* __restrict__ c,      // [T*B]
    const float*  __restrict__ st,     // [B][64]
    const float*  __restrict__ W_hh,   // [3][3]
    const float*  __restrict__ W_fc,   // [32][67]
    const float*  __restrict__ b_fc,   // [32]
    float* __restrict__ out)           // [B][32]
{
    const int b = blockIdx.x * 64 + threadIdx.x;
    const float w00=W_hh[0], w01=W_hh[1], w02=W_hh[2];
    const float w10=W_hh[3], w11=W_hh[4], w12=W_hh[5];
    const float w20=W_hh[6], w21=W_hh[7], w22=W_hh[8];

    float h0=0.f, h1=0.f, h2=0.f, s0=0.f, s1=0.f, s2=0.f;
    const float4* cp = c + b;

    float4 f[PF];
    #pragma unroll
    for (int i = 0; i < PF; ++i) f[i] = cp[(size_t)i * BB];

#define STEP(c0, c1, c2) do {                                              \
        const float n0 = fmaxf(fmaf(w02,h2,fmaf(w01,h1,fmaf(w00,h0,(c0)))), 0.f); \
        const float n1 = fmaxf(fmaf(w12,h2,fmaf(w11,h1,fmaf(w10,h0,(c1)))), 0.f); \
        const float n2 = fmaxf(fmaf(w22,h2,fmaf(w21,h1,fmaf(w20,h0,(c2)))), 0.f); \
        h0 = n0; h1 = n1; h2 = n2;                                         \
        s0 += n0; s1 += n1; s2 += n2;                                      \
    } while (0)

    for (int t0 = 0; t0 < TT - PF; t0 += PF) {
        #pragma unroll
        for (int i = 0; i < PF; ++i) {
            const float c0 = f[i].x, c1 = f[i].y, c2 = f[i].z;
            f[i] = cp[(size_t)(t0 + PF + i) * BB];   // prefetch PF steps ahead
            STEP(c0, c1, c2);
        }
    }
    #pragma unroll
    for (int i = 0; i < PF; ++i) STEP(f[i].x, f[i].y, f[i].z);
#undef STEP

    const float inv = 1.0f / (float)TT;
    const float m0 = s0 * inv, m1 = s1 * inv, m2 = s2 * inv;

    float4 stv[16];
    const float4* st4 = reinterpret_cast<const float4*>(st) + b * 16;
    #pragma unroll
    for (int i = 0; i < 16; ++i) stv[i] = st4[i];

    for (int o = 0; o < NOUT; ++o) {
        const float* w = W_fc + o * (FST + HH);
        float acc = b_fc[o];
        #pragma unroll
        for (int i = 0; i < 16; ++i)
            acc += stv[i].x * w[4*i+0] + stv[i].y * w[4*i+1]
                 + stv[i].z * w[4*i+2] + stv[i].w * w[4*i+3];
        acc += m0 * w[FST] + m1 * w[FST + 1] + m2 * w[FST + 2];
        out[b * NOUT + o] = acc;
    }
}

extern "C" void kernel_launch(void* const* d_in, const int* in_sizes, int n_in,
                              void* d_out, int out_size, void* d_ws, size_t ws_size,
                              hipStream_t stream)
{
    const float* tr   = (const float*)d_in[0];
    const float* st   = (const float*)d_in[1];
    const float* W_ih = (const float*)d_in[2];
    const float* W_hh = (const float*)d_in[3];
    const float* b_ih = (const float*)d_in[4];
    const float* b_hh = (const float*)d_in[5];
    const float* W_fc = (const float*)d_in[6];
    const float* b_fc = (const float*)d_in[7];

    float* c = (float*)d_ws;   // needs T*B*4 floats = 8 MB scratch

    k1_proj<<<dim3(2048), dim3(256), 0, stream>>>(tr, W_ih, b_ih, b_hh, c);
    k2_scan<<<dim3(4), dim3(64), 0, stream>>>(
        (const float4*)c, st, W_hh, W_fc, b_fc, (float*)d_out);
}

// Round 2
// 144.122 us; speedup vs baseline: 1.0736x; 1.0736x over previous
//
#include <hip/hip_runtime.h>

// Problem constants
#define BB   256
#define TT   2048
#define FTR  128
#define FST  64
#define HH   3
#define NOUT 32
#define TBSZ (TT * BB)
#define PF   16   // k2 double-buffer phase length (steps)

// ---------------------------------------------------------------------------
// k1: c[(t*B+b)] = float4(xW[b,t,0..2] + b_ih + b_hh, <unused>)
// 16 lanes per (b,t) row, 4 rows per wave. Coalesced float4 reads of tr_input,
// shfl_xor butterfly reduction over 16 lanes for the 3 dot products.
// (UNCHANGED from round 1 — attribution: any dur delta this round is k2.)
// ---------------------------------------------------------------------------
__global__ __launch_bounds__(256) void k1_proj(
    const float* __restrict__ tr,      // [B][T][128]
    const float* __restrict__ W_ih,    // [3][128]
    const float* __restrict__ b_ih,    // [3]
    const float* __restrict__ b_hh,    // [3]
    float* __restrict__ c)             // [T*B] float4 (stored as floats)
{
    const int lane = threadIdx.x & 63;
    const int sub  = lane & 15;        // element slice within row
    const int quad = lane >> 4;        // which of 4 rows in the group
    const int wave   = blockIdx.x * (blockDim.x >> 6) + (threadIdx.x >> 6);
    const int nwaves = gridDim.x * (blockDim.x >> 6);

    const float4* W4 = reinterpret_cast<const float4*>(W_ih);  // [3][32]
    const float4 wA0 = W4[       sub], wA1 = W4[16 + sub];
    const float4 wB0 = W4[32   + sub], wB1 = W4[48 + sub];
    const float4 wC0 = W4[64   + sub], wC1 = W4[80 + sub];
    const float bias = (sub < 3) ? (b_ih[sub] + b_hh[sub]) : 0.0f;

    const float4* in4 = reinterpret_cast<const float4*>(tr);
    const int ngroups = TBSZ / 4;      // group = 4 consecutive b at same t
    for (int g = wave; g < ngroups; g += nwaves) {
        const int t = g >> 6;                    // g / 64
        const int b = ((g & 63) << 2) + quad;    // 4 consecutive b per group
        const int rowb = (b * TT + t) * (FTR / 4);
        const float4 x0 = in4[rowb + sub];       // elems 4*sub .. 4*sub+3
        const float4 x1 = in4[rowb + 16 + sub];  // elems 64+4*sub ..
        float p0 = x0.x*wA0.x + x0.y*wA0.y + x0.z*wA0.z + x0.w*wA0.w
                 + x1.x*wA1.x + x1.y*wA1.y + x1.z*wA1.z + x1.w*wA1.w;
        float p1 = x0.x*wB0.x + x0.y*wB0.y + x0.z*wB0.z + x0.w*wB0.w
                 + x1.x*wB1.x + x1.y*wB1.y + x1.z*wB1.z + x1.w*wB1.w;
        float p2 = x0.x*wC0.x + x0.y*wC0.y + x0.z*wC0.z + x0.w*wC0.w
                 + x1.x*wC1.x + x1.y*wC1.y + x1.z*wC1.z + x1.w*wC1.w;
        #pragma unroll
        for (int m = 1; m <= 8; m <<= 1) {       // 16-lane butterfly (DPP-able)
            p0 += __shfl_xor(p0, m);
            p1 += __shfl_xor(p1, m);
            p2 += __shfl_xor(p2, m);
        }
        if (sub < 3) {
            const float v = (sub == 0) ? p0 : ((sub == 1) ? p1 : p2);
            c[((t * BB + b) << 2) + sub] = v + bias;
        }
    }
}

// ---------------------------------------------------------------------------
// k2: sequential relu-RNN scan, one lane per batch element, plus FC epilogue.
// Two-phase double buffer with NAMED register arrays: loads for buffer B are
// clustered at phase top, then 16 steps consume buffer A. Even a conservative
// wait-all before B's first use lands after ~672 cy of independent compute,
// covering LLC latency. No per-step register rotation movs.
// ---------------------------------------------------------------------------
__global__ __launch_bounds__(64) void k2_scan(
    const float4* __restrict__ c,      // [T*B]
    const float*  __restrict__ st,     // [B][64]
    const float*  __restrict__ W_hh,   // [3][3]
    const float*  __restrict__ W_fc,   // [32][67]
    const float*  __restrict__ b_fc,   // [32]
    float* __restrict__ out)           // [B][32]
{
    const int b = blockIdx.x * 64 + threadIdx.x;
    const float w00=W_hh[0], w01=W_hh[1], w02=W_hh[2];
    const float w10=W_hh[3], w11=W_hh[4], w12=W_hh[5];
    const float w20=W_hh[6], w21=W_hh[7], w22=W_hh[8];

    float h0=0.f, h1=0.f, h2=0.f, s0=0.f, s1=0.f, s2=0.f;
    const float4* cp = c + b;

    float4 fA[PF], fB[PF];

#define STEP(c0, c1, c2) do {                                              \
        const float n0 = fmaxf(fmaf(w02,h2,fmaf(w01,h1,fmaf(w00,h0,(c0)))), 0.f); \
        const float n1 = fmaxf(fmaf(w12,h2,fmaf(w11,h1,fmaf(w10,h0,(c1)))), 0.f); \
        const float n2 = fmaxf(fmaf(w22,h2,fmaf(w21,h1,fmaf(w20,h0,(c2)))), 0.f); \
        h0 = n0; h1 = n1; h2 = n2;                                         \
        s0 += n0; s1 += n1; s2 += n2;                                      \
    } while (0)

    // prologue: fA <- t[0..15]
    #pragma unroll
    for (int i = 0; i < PF; ++i) fA[i] = cp[i * BB];

    // main loop: 63 iterations, each = 2 phases of 16 steps
    for (int t0 = 0; t0 < TT - 2 * PF; t0 += 2 * PF) {
        #pragma unroll
        for (int i = 0; i < PF; ++i) fB[i] = cp[(t0 + PF + i) * BB];
        #pragma unroll
        for (int i = 0; i < PF; ++i) STEP(fA[i].x, fA[i].y, fA[i].z);
        #pragma unroll
        for (int i = 0; i < PF; ++i) fA[i] = cp[(t0 + 2 * PF + i) * BB];
        #pragma unroll
        for (int i = 0; i < PF; ++i) STEP(fB[i].x, fB[i].y, fB[i].z);
    }
    // after loop: consumed t < 2016; fA holds t = 2016..2031
    #pragma unroll
    for (int i = 0; i < PF; ++i) fB[i] = cp[(TT - PF + i) * BB];
    #pragma unroll
    for (int i = 0; i < PF; ++i) STEP(fA[i].x, fA[i].y, fA[i].z);
    #pragma unroll
    for (int i = 0; i < PF; ++i) STEP(fB[i].x, fB[i].y, fB[i].z);
#undef STEP

    const float inv = 1.0f / (float)TT;
    const float m0 = s0 * inv, m1 = s1 * inv, m2 = s2 * inv;

    float4 stv[16];
    const float4* st4 = reinterpret_cast<const float4*>(st) + b * 16;
    #pragma unroll
    for (int i = 0; i < 16; ++i) stv[i] = st4[i];

    for (int o = 0; o < NOUT; ++o) {
        const float* w = W_fc + o * (FST + HH);
        float acc = b_fc[o];
        #pragma unroll
        for (int i = 0; i < 16; ++i)
            acc += stv[i].x * w[4*i+0] + stv[i].y * w[4*i+1]
                 + stv[i].z * w[4*i+2] + stv[i].w * w[4*i+3];
        acc += m0 * w[FST] + m1 * w[FST + 1] + m2 * w[FST + 2];
        out[b * NOUT + o] = acc;
    }
}

extern "C" void kernel_launch(void* const* d_in, const int* in_sizes, int n_in,
                              void* d_out, int out_size, void* d_ws, size_t ws_size,
                              hipStream_t stream)
{
    const float* tr   = (const float*)d_in[0];
    const float* st   = (const float*)d_in[1];
    const float* W_ih = (const float*)d_in[2];
    const float* W_hh = (const float*)d_in[3];
    const float* b_ih = (const float*)d_in[4];
    const float* b_hh = (const float*)d_in[5];
    const float* W_fc = (const float*)d_in[6];
    const float* b_fc = (const float*)d_in[7];

    float* c = (float*)d_ws;   // needs T*B*4 floats = 8 MB scratch

    k1_proj<<<dim3(2048), dim3(256), 0, stream>>>(tr, W_ih, b_ih, b_hh, c);
    k2_scan<<<dim3(4), dim3(64), 0, stream>>>(
        (const float4*)c, st, W_hh, W_fc, b_fc, (float*)d_out);
}